// Round 12
// baseline (980.121 us; speedup 1.0000x reference)
//
#include <hip/hip_runtime.h>

#define EPS 1e-5f

typedef __attribute__((ext_vector_type(8))) short short8;
typedef __attribute__((ext_vector_type(4))) float float4v;

__device__ __forceinline__ unsigned short f2bf(float x) {
  unsigned int u = __builtin_bit_cast(unsigned int, x);
  u += 0x7fffu + ((u >> 16) & 1u);   // RNE to bf16
  return (unsigned short)(u >> 16);
}
__device__ __forceinline__ float bf2f(unsigned short h) {
  unsigned int u = ((unsigned int)h) << 16;
  return __builtin_bit_cast(float, u);
}

__device__ __forceinline__ void gl_lds16(const void* g, void* l) {
  __builtin_amdgcn_global_load_lds(
      (const __attribute__((address_space(1))) unsigned int*)g,
      (__attribute__((address_space(3))) unsigned int*)l, 16, 0, 0);
}

// ---------------- Kernel 0: Wv fp32 [d][e] -> bf16 [e][k] swizzled image ----------------
// grid 4225 = (nq*65+m); thread t owns e-row t. Reads 128 floats at 1KB stride
// (wave = 256B contiguous segments); writes 16x 16B chunks at XOR'd positions.
// Output image == exactly the LDS bytes attnv wants (linear global_load_lds).
__global__ __launch_bounds__(256) void conv_kernel(
    const float* __restrict__ Wv, unsigned short* __restrict__ Wvb) {
  const int blk = blockIdx.x;
  const int t = threadIdx.x;
  const float* src = Wv + (size_t)blk * 32768 + t;          // elem (d, e=t) at d*256+t
  char* dst = (char*)Wvb + (size_t)blk * 65536 + t * 256;   // e-row t, 256B
  const int x = t & 15;
#pragma unroll
  for (int p = 0; p < 8; p++) {
    float v[16];
#pragma unroll
    for (int j = 0; j < 16; j++)
      v[j] = __builtin_nontemporal_load(src + (size_t)(p * 16 + j) * 256);
    short8 a, b;
#pragma unroll
    for (int j = 0; j < 8; j++) {
      a[j] = (short)f2bf(v[j]);
      b[j] = (short)f2bf(v[8 + j]);
    }
    *(short8*)(dst + (((2 * p) ^ x) << 4)) = a;
    *(short8*)(dst + (((2 * p + 1) ^ x) << 4)) = b;
  }
}

// ---------------- Kernel 1: LayerNorm ----------------
__global__ __launch_bounds__(256) void ln_kernel(
    const float* __restrict__ x, const float* __restrict__ gamma,
    const float* __restrict__ beta, float* __restrict__ xn) {
  const int row = blockIdx.x * 4 + (threadIdx.x >> 6);
  const int lane = threadIdx.x & 63;
  const float2 v = ((const float2*)(x + (size_t)row * 128))[lane];
  float s = v.x + v.y;
#pragma unroll
  for (int off = 1; off < 64; off <<= 1) s += __shfl_xor(s, off);
  const float mu = s * (1.f / 128.f);
  const float dx = v.x - mu, dy = v.y - mu;
  float qv = dx * dx + dy * dy;
#pragma unroll
  for (int off = 1; off < 64; off <<= 1) qv += __shfl_xor(qv, off);
  const float rstd = 1.f / sqrtf(qv * (1.f / 128.f) + EPS);
  const float2 g = ((const float2*)gamma)[lane];
  const float2 be = ((const float2*)beta)[lane];
  float2 o;
  o.x = dx * rstd * g.x + be.x;
  o.y = dy * rstd * g.y + be.y;
  ((float2*)(xn + (size_t)row * 128))[lane] = o;
}

// ---------------- Kernel 2: qk = xn @ Wqk  [4160,128]x[128,512] ----------------
__global__ __launch_bounds__(256) void qk_kernel(
    const float* __restrict__ xn, const float* __restrict__ Wqk,
    float* __restrict__ qk) {
  __shared__ float xsx[32][130];
  __shared__ float wsx[128][68];
  const int t = threadIdx.x;
  const int r0 = blockIdx.x * 32, c0 = blockIdx.y * 64;
  for (int i = t; i < 32 * 32; i += 256) {
    int r = i >> 5, c = (i & 31) << 2;
    float4 v = *(const float4*)(xn + (size_t)(r0 + r) * 128 + c);
    float* dst = &xsx[r][c];
    dst[0] = v.x; dst[1] = v.y; dst[2] = v.z; dst[3] = v.w;
  }
  for (int i = t; i < 128 * 16; i += 256) {
    int k = i >> 4, c = (i & 15) << 2;
    *(float4*)&wsx[k][c] = *(const float4*)(Wqk + (size_t)k * 512 + c0 + c);
  }
  __syncthreads();
  const int rr = (t >> 4) * 2, cc = (t & 15) * 4;
  float acc[2][4] = {{0.f, 0.f, 0.f, 0.f}, {0.f, 0.f, 0.f, 0.f}};
  for (int k = 0; k < 128; k++) {
    float4 wv4 = *(const float4*)&wsx[k][cc];
    float x0 = xsx[rr][k], x1 = xsx[rr + 1][k];
    acc[0][0] += x0 * wv4.x; acc[0][1] += x0 * wv4.y;
    acc[0][2] += x0 * wv4.z; acc[0][3] += x0 * wv4.w;
    acc[1][0] += x1 * wv4.x; acc[1][1] += x1 * wv4.y;
    acc[1][2] += x1 * wv4.z; acc[1][3] += x1 * wv4.w;
  }
#pragma unroll
  for (int r = 0; r < 2; r++) {
    float4 o;
    o.x = acc[r][0]; o.y = acc[r][1]; o.z = acc[r][2]; o.w = acc[r][3];
    *(float4*)(qk + (size_t)(r0 + rr + r) * 512 + c0 + cc) = o;
  }
}

// ---------------- Kernel 3: dots + softmax ----------------
__global__ __launch_bounds__(256) void softmax_kernel(
    const float* __restrict__ qk, float* __restrict__ attn) {
  const int b = blockIdx.x >> 3, h = blockIdx.x & 7;
  __shared__ float qs[65][33];
  __shared__ float ks[65][33];
  __shared__ float dotsS[65][66];
  __shared__ float rsum[65];
  const int t = threadIdx.x;
  for (int i = t; i < 65 * 32; i += 256) {
    int n = i >> 5, d = i & 31;
    size_t base = ((size_t)b * 65 + n) * 512 + h * 32 + d;
    qs[n][d] = qk[base];
    ks[n][d] = qk[base + 256];
  }
  __syncthreads();
  const float scale = 0.17677669529663687f;  // 1/sqrt(32)
  for (int i = t; i < 65 * 65; i += 256) {
    int n = i / 65, mm = i - n * 65;
    float s = 0.f;
#pragma unroll
    for (int d = 0; d < 32; d++) s += qs[n][d] * ks[mm][d];
    dotsS[n][mm] = s * scale;
  }
  __syncthreads();
  if (t < 65) {
    float mx = -1e30f;
    for (int mm = 0; mm < 65; mm++) mx = fmaxf(mx, dotsS[t][mm]);
    float sum = 0.f;
    for (int mm = 0; mm < 65; mm++) {
      float e = __expf(dotsS[t][mm] - mx);
      dotsS[t][mm] = e;
      sum += e;
    }
    rsum[t] = 1.f / sum;
  }
  __syncthreads();
  const size_t obase = ((size_t)b * 8 + h) * 65 * 65;
  for (int i = t; i < 65 * 65; i += 256) {
    int n = i / 65;
    attn[obase + i] = dotsS[n][i - n * 65] * rsum[n];
  }
}

// ---------------- Kernel 4: big contraction, bf16-image + global_load_lds DMA ----------------
// grid (130, 8): bx = nq*2+eh (e-half of 128 cols), by = mc (8 m-chunks of 8-9).
// 256 thr / 4 waves = 2 rg x 2 cg. Per m: DMA 32KB bf16 (pre-swizzled) into LDS
// dbuf via global_load_lds w=16 (no VGPR staging, no conversion). 74.8KB LDS ->
// 2 blocks/CU; co-resident block's MFMA covers the barrier vmcnt drain.
// Partial sums -> inner_p[mc] with plain stores (no atomics).
__global__ __launch_bounds__(256, 2) void attnv_kernel(
    const float* __restrict__ xn, const float* __restrict__ attn,
    const unsigned short* __restrict__ Wvb, float* __restrict__ inner_p) {
  __shared__ __align__(16) char sbuf[65536];  // xs[64][130] f32 (33.3KB) OR dbuf 2x32KB bf16
  __shared__ float attnL[9 * 4 * 64];         // [mloc][hloc][b]
  float* xs = (float*)sbuf;
  unsigned short* wvb = (unsigned short*)sbuf;

  const int nq = blockIdx.x >> 1, eh = blockIdx.x & 1;
  const int mc = blockIdx.y;
  const int ms = (mc * 65) >> 3;
  const int cnt = (((mc + 1) * 65) >> 3) - ms;  // 8 (x7) or 9 (last)

  const int t = threadIdx.x;
  const int lane = t & 63;
  const int w = t >> 6;
  const int er = lane & 15, q = lane >> 4;
  const int rg = w & 1, cg = w >> 1;  // rows rg*32..+31, e-cols (local) cg*64..+63
  const int woff = w * 8192;          // this wave's 8KB slice of a 32KB buffer

  const char* wvblk = (const char*)Wvb + ((size_t)nq * 65 + ms) * 65536 + eh * 32768;

  // ---- prologue A: xn rows -> xs, then A-fragments (hi/lo bf16) ----
  for (int i = t; i < 64 * 32; i += 256) {
    int b = i >> 5, c = (i & 31) << 2;
    float4 v = *(const float4*)(xn + ((size_t)b * 65 + nq) * 128 + c);
    float* dst = xs + b * 130 + c;
    dst[0] = v.x; dst[1] = v.y; dst[2] = v.z; dst[3] = v.w;
  }
  __syncthreads();
  short8 ah[2][4], al[2][4];
#pragma unroll
  for (int rt = 0; rt < 2; rt++) {
    const int arow = rg * 32 + rt * 16 + er;
#pragma unroll
    for (int s = 0; s < 4; s++) {
#pragma unroll
      for (int j = 0; j < 8; j++) {
        float xv = xs[arow * 130 + s * 32 + q * 8 + j];
        unsigned short hi = f2bf(xv);
        ah[rt][s][j] = (short)hi;
        al[rt][s][j] = (short)f2bf(xv - bf2f(hi));
      }
    }
  }
  __syncthreads();  // xs dead; sbuf becomes the Wv double buffer

  // ---- prologue B: DMA m=ms into buf0; attn chunk -> attnL ----
  {
#pragma unroll
    for (int j = 0; j < 8; j++)
      gl_lds16(wvblk + woff + j * 1024 + (lane << 4),
               (char*)wvb + woff + j * 1024);
  }
  {
    const int hloc = t >> 6, b = t & 63;
    const int hg = eh * 4 + hloc;
    for (int mloc = 0; mloc < cnt; mloc++)
      attnL[(mloc * 4 + hloc) * 64 + b] =
          attn[(((size_t)(b * 8 + hg)) * 65 + nq) * 65 + ms + mloc];
  }
  __syncthreads();  // drains gl_lds (vmcnt) + attnL visible

  float4v acc[2][4];
#pragma unroll
  for (int rt = 0; rt < 2; rt++)
#pragma unroll
    for (int ct = 0; ct < 4; ct++)
      acc[rt][ct] = (float4v){0.f, 0.f, 0.f, 0.f};

  for (int i = 0; i < cnt; i++) {
    if (i + 1 < cnt) {  // DMA next m into the other buffer (in flight across MFMA)
      const char* gs = wvblk + (size_t)(i + 1) * 65536;
      char* ls = (char*)wvb + ((i + 1) & 1) * 32768;
#pragma unroll
      for (int j = 0; j < 8; j++)
        gl_lds16(gs + woff + j * 1024 + (lane << 4), ls + woff + j * 1024);
    }
    const unsigned short* wb = wvb + (i & 1) * 16384;
    float4v P[2][4];
#pragma unroll
    for (int rt = 0; rt < 2; rt++)
#pragma unroll
      for (int ct = 0; ct < 4; ct++)
        P[rt][ct] = (float4v){0.f, 0.f, 0.f, 0.f};
    __builtin_amdgcn_s_setprio(1);
#pragma unroll
    for (int s = 0; s < 4; s++) {
      const int kc = 4 * s + q;
#pragma unroll
      for (int ct = 0; ct < 4; ct++) {
        // local e-row = cg*64+ct*16+er; (e&15)==er so swizzle matches conv_kernel
        short8 bf = *(const short8*)&wb[(cg * 64 + ct * 16 + er) * 128 + ((kc ^ er) << 3)];
        P[0][ct] = __builtin_amdgcn_mfma_f32_16x16x32_bf16(ah[0][s], bf, P[0][ct], 0, 0, 0);
        P[0][ct] = __builtin_amdgcn_mfma_f32_16x16x32_bf16(al[0][s], bf, P[0][ct], 0, 0, 0);
        P[1][ct] = __builtin_amdgcn_mfma_f32_16x16x32_bf16(ah[1][s], bf, P[1][ct], 0, 0, 0);
        P[1][ct] = __builtin_amdgcn_mfma_f32_16x16x32_bf16(al[1][s], bf, P[1][ct], 0, 0, 0);
      }
    }
    __builtin_amdgcn_s_setprio(0);
#pragma unroll
    for (int rt = 0; rt < 2; rt++) {
#pragma unroll
      for (int ct = 0; ct < 4; ct++) {
        const int hl = cg * 2 + (ct >> 1);
        const float* ap = attnL + (i * 4 + hl) * 64 + rg * 32 + rt * 16 + q * 4;
#pragma unroll
        for (int r = 0; r < 4; r++) acc[rt][ct][r] += ap[r] * P[rt][ct][r];
      }
    }
    __syncthreads();
  }

  // ---- epilogue: plain stores into this mc's private partial buffer ----
  float* ip = inner_p + (size_t)mc * 1064960;
#pragma unroll
  for (int rt = 0; rt < 2; rt++) {
#pragma unroll
    for (int ct = 0; ct < 4; ct++) {
      const int ecol = eh * 128 + cg * 64 + ct * 16 + er;
#pragma unroll
      for (int r = 0; r < 4; r++) {
        const int b = rg * 32 + rt * 16 + q * 4 + r;
        ip[((size_t)b * 65 + nq) * 256 + ecol] = acc[rt][ct][r];
      }
    }
  }
}

// ---------------- Kernel 5: out = (sum_j inner_p[j]) @ Wout + bout ----------------
__global__ __launch_bounds__(256) void outproj_kernel(
    const float* __restrict__ inner_p, const float* __restrict__ Wout,
    const float* __restrict__ bout, float* __restrict__ out) {
  __shared__ float isx[16][258];
  __shared__ float wsx[64][132];
  const int t = threadIdx.x;
  const int r0 = blockIdx.x * 16;
  for (int i = t; i < 16 * 64; i += 256) {
    int r = i >> 6, c = (i & 63) << 2;
    float4 a;
    a.x = 0.f; a.y = 0.f; a.z = 0.f; a.w = 0.f;
#pragma unroll
    for (int jj = 0; jj < 8; jj++) {
      float4 v = *(const float4*)(inner_p + (size_t)jj * 1064960 +
                                  (size_t)(r0 + r) * 256 + c);
      a.x += v.x; a.y += v.y; a.z += v.z; a.w += v.w;
    }
    float* dst = &isx[r][c];
    dst[0] = a.x; dst[1] = a.y; dst[2] = a.z; dst[3] = a.w;
  }
  const int rr = (t >> 5) * 2, cc = (t & 31) * 4;
  float acc[2][4] = {{0.f, 0.f, 0.f, 0.f}, {0.f, 0.f, 0.f, 0.f}};
  for (int kc = 0; kc < 4; kc++) {
    __syncthreads();
    for (int i = t; i < 64 * 32; i += 256) {
      int k = i >> 5, c = (i & 31) << 2;
      *(float4*)&wsx[k][c] = *(const float4*)(Wout + (size_t)(kc * 64 + k) * 128 + c);
    }
    __syncthreads();
#pragma unroll 8
    for (int k = 0; k < 64; k++) {
      float4 wv4 = *(const float4*)&wsx[k][cc];
      float x0 = isx[rr][kc * 64 + k];
      float x1 = isx[rr + 1][kc * 64 + k];
      acc[0][0] += x0 * wv4.x; acc[0][1] += x0 * wv4.y;
      acc[0][2] += x0 * wv4.z; acc[0][3] += x0 * wv4.w;
      acc[1][0] += x1 * wv4.x; acc[1][1] += x1 * wv4.y;
      acc[1][2] += x1 * wv4.z; acc[1][3] += x1 * wv4.w;
    }
  }
  float4 bb = *(const float4*)(bout + cc);
#pragma unroll
  for (int r = 0; r < 2; r++) {
    float4 o;
    o.x = acc[r][0] + bb.x; o.y = acc[r][1] + bb.y;
    o.z = acc[r][2] + bb.z; o.w = acc[r][3] + bb.w;
    *(float4*)(out + (size_t)(r0 + rr + r) * 128 + cc) = o;
  }
}

extern "C" void kernel_launch(void* const* d_in, const int* in_sizes, int n_in,
                              void* d_out, int out_size, void* d_ws, size_t ws_size,
                              hipStream_t stream) {
  const float* x     = (const float*)d_in[0];
  const float* gamma = (const float*)d_in[1];
  const float* beta  = (const float*)d_in[2];
  const float* Wqk   = (const float*)d_in[3];
  const float* Wv    = (const float*)d_in[4];
  const float* Wout  = (const float*)d_in[5];
  const float* bout  = (const float*)d_in[6];
  float* out = (float*)d_out;
  float* ws  = (float*)d_ws;

  float* xn      = ws;                    // 532,480 floats
  float* qk      = ws + 532480;           // 2,129,920
  float* attn    = ws + 2662400;          // 2,163,200
  float* inner_p = ws + 4825600;          // 8 x 1,064,960 = 8,519,680
  unsigned short* Wvb = (unsigned short*)(ws + 13500032);  // 276.9 MB bf16 image

  conv_kernel<<<4225, 256, 0, stream>>>(Wv, Wvb);
  ln_kernel<<<1040, 256, 0, stream>>>(x, gamma, beta, xn);
  qk_kernel<<<dim3(130, 8), 256, 0, stream>>>(xn, Wqk, qk);
  softmax_kernel<<<512, 256, 0, stream>>>(qk, attn);
  attnv_kernel<<<dim3(130, 8), 256, 0, stream>>>(xn, attn, Wvb, inner_p);
  outproj_kernel<<<260, 256, 0, stream>>>(inner_p, Wout, bout, out);
}

// Round 16
// 892.738 us; speedup vs baseline: 1.0979x; 1.0979x over previous
//
#include <hip/hip_runtime.h>

#define EPS 1e-5f

typedef __attribute__((ext_vector_type(8))) short short8;
typedef __attribute__((ext_vector_type(4))) short short4v;
typedef __attribute__((ext_vector_type(4))) float float4v;

__device__ __forceinline__ unsigned short f2bf(float x) {
  unsigned int u = __builtin_bit_cast(unsigned int, x);
  u += 0x7fffu + ((u >> 16) & 1u);   // RNE to bf16
  return (unsigned short)(u >> 16);
}
__device__ __forceinline__ float bf2f(unsigned short h) {
  unsigned int u = ((unsigned int)h) << 16;
  return __builtin_bit_cast(float, u);
}

__device__ __forceinline__ void gl_lds16(const void* g, void* l) {
  __builtin_amdgcn_global_load_lds(
      (const __attribute__((address_space(1))) unsigned int*)g,
      (__attribute__((address_space(3))) unsigned int*)l, 16, 0, 0);
}

// ---------------- Kernel 0 v3: Wv fp32 [d][e] -> bf16 [e][k] swizzled image ----------------
// grid 4225 = (nq*65+m). VECTORIZED reads (G13): wave = 64 x float4 = one full
// contiguous 1KB row per instruction (m13's 6.3TB/s recipe). LDS transpose
// T[d][e] (66.6KB), then write-out: 16-lane group emits one full 256B e-row
// (16 chunks, XOR-permuted) -> 1KB contiguous per wave store instruction.
// Image is byte-identical to the r12 conv output.
__global__ __launch_bounds__(256) void conv_kernel(
    const float* __restrict__ Wv, unsigned short* __restrict__ Wvb) {
  __shared__ unsigned short T[128][260];  // [d][e], pad->bank-friendly
  const int blk = blockIdx.x;
  const int t = threadIdx.x;
  const float* src = Wv + (size_t)blk * 32768;
  char* dst = (char*)Wvb + (size_t)blk * 65536;

  // read+convert: 32 passes x 4 rows; wave w handles row pass*4+w fully
  const int rw = t >> 6, c4 = t & 63;
#pragma unroll 4
  for (int pass = 0; pass < 32; pass++) {
    const int r = pass * 4 + rw;
    float4 v = *(const float4*)(src + (size_t)r * 256 + c4 * 4);
    short4v p;
    p[0] = (short)f2bf(v.x); p[1] = (short)f2bf(v.y);
    p[2] = (short)f2bf(v.z); p[3] = (short)f2bf(v.w);
    *(short4v*)&T[r][c4 * 4] = p;   // 8B, aligned (row=520B, c4*8B)
  }
  __syncthreads();

  // write-out: iter it: lane l -> e = it*16 + (l>>4), chunk gc = l&15.
  // 16-lane group covers one full 256B e-row; wave = 4 rows = 1KB contiguous.
  const int gc = t & 15;
#pragma unroll
  for (int it = 0; it < 16; it++) {
    const int e = it * 16 + (t >> 4);
    short8 pk;
#pragma unroll
    for (int j = 0; j < 8; j++) pk[j] = (short)T[gc * 8 + j][e];
    *(short8*)(dst + e * 256 + ((gc ^ (e & 15)) << 4)) = pk;
  }
}

// ---------------- Kernel 1: LayerNorm ----------------
__global__ __launch_bounds__(256) void ln_kernel(
    const float* __restrict__ x, const float* __restrict__ gamma,
    const float* __restrict__ beta, float* __restrict__ xn) {
  const int row = blockIdx.x * 4 + (threadIdx.x >> 6);
  const int lane = threadIdx.x & 63;
  const float2 v = ((const float2*)(x + (size_t)row * 128))[lane];
  float s = v.x + v.y;
#pragma unroll
  for (int off = 1; off < 64; off <<= 1) s += __shfl_xor(s, off);
  const float mu = s * (1.f / 128.f);
  const float dx = v.x - mu, dy = v.y - mu;
  float qv = dx * dx + dy * dy;
#pragma unroll
  for (int off = 1; off < 64; off <<= 1) qv += __shfl_xor(qv, off);
  const float rstd = 1.f / sqrtf(qv * (1.f / 128.f) + EPS);
  const float2 g = ((const float2*)gamma)[lane];
  const float2 be = ((const float2*)beta)[lane];
  float2 o;
  o.x = dx * rstd * g.x + be.x;
  o.y = dy * rstd * g.y + be.y;
  ((float2*)(xn + (size_t)row * 128))[lane] = o;
}

// ---------------- Kernel 2: qk = xn @ Wqk  [4160,128]x[128,512] ----------------
__global__ __launch_bounds__(256) void qk_kernel(
    const float* __restrict__ xn, const float* __restrict__ Wqk,
    float* __restrict__ qk) {
  __shared__ float xsx[32][130];
  __shared__ float wsx[128][68];
  const int t = threadIdx.x;
  const int r0 = blockIdx.x * 32, c0 = blockIdx.y * 64;
  for (int i = t; i < 32 * 32; i += 256) {
    int r = i >> 5, c = (i & 31) << 2;
    float4 v = *(const float4*)(xn + (size_t)(r0 + r) * 128 + c);
    float* dst = &xsx[r][c];
    dst[0] = v.x; dst[1] = v.y; dst[2] = v.z; dst[3] = v.w;
  }
  for (int i = t; i < 128 * 16; i += 256) {
    int k = i >> 4, c = (i & 15) << 2;
    *(float4*)&wsx[k][c] = *(const float4*)(Wqk + (size_t)k * 512 + c0 + c);
  }
  __syncthreads();
  const int rr = (t >> 4) * 2, cc = (t & 15) * 4;
  float acc[2][4] = {{0.f, 0.f, 0.f, 0.f}, {0.f, 0.f, 0.f, 0.f}};
  for (int k = 0; k < 128; k++) {
    float4 wv4 = *(const float4*)&wsx[k][cc];
    float x0 = xsx[rr][k], x1 = xsx[rr + 1][k];
    acc[0][0] += x0 * wv4.x; acc[0][1] += x0 * wv4.y;
    acc[0][2] += x0 * wv4.z; acc[0][3] += x0 * wv4.w;
    acc[1][0] += x1 * wv4.x; acc[1][1] += x1 * wv4.y;
    acc[1][2] += x1 * wv4.z; acc[1][3] += x1 * wv4.w;
  }
#pragma unroll
  for (int r = 0; r < 2; r++) {
    float4 o;
    o.x = acc[r][0]; o.y = acc[r][1]; o.z = acc[r][2]; o.w = acc[r][3];
    *(float4*)(qk + (size_t)(r0 + rr + r) * 512 + c0 + cc) = o;
  }
}

// ---------------- Kernel 3: dots + softmax ----------------
__global__ __launch_bounds__(256) void softmax_kernel(
    const float* __restrict__ qk, float* __restrict__ attn) {
  const int b = blockIdx.x >> 3, h = blockIdx.x & 7;
  __shared__ float qs[65][33];
  __shared__ float ks[65][33];
  __shared__ float dotsS[65][66];
  __shared__ float rsum[65];
  const int t = threadIdx.x;
  for (int i = t; i < 65 * 32; i += 256) {
    int n = i >> 5, d = i & 31;
    size_t base = ((size_t)b * 65 + n) * 512 + h * 32 + d;
    qs[n][d] = qk[base];
    ks[n][d] = qk[base + 256];
  }
  __syncthreads();
  const float scale = 0.17677669529663687f;  // 1/sqrt(32)
  for (int i = t; i < 65 * 65; i += 256) {
    int n = i / 65, mm = i - n * 65;
    float s = 0.f;
#pragma unroll
    for (int d = 0; d < 32; d++) s += qs[n][d] * ks[mm][d];
    dotsS[n][mm] = s * scale;
  }
  __syncthreads();
  if (t < 65) {
    float mx = -1e30f;
    for (int mm = 0; mm < 65; mm++) mx = fmaxf(mx, dotsS[t][mm]);
    float sum = 0.f;
    for (int mm = 0; mm < 65; mm++) {
      float e = __expf(dotsS[t][mm] - mx);
      dotsS[t][mm] = e;
      sum += e;
    }
    rsum[t] = 1.f / sum;
  }
  __syncthreads();
  const size_t obase = ((size_t)b * 8 + h) * 65 * 65;
  for (int i = t; i < 65 * 65; i += 256) {
    int n = i / 65;
    attn[obase + i] = dotsS[n][i - n * 65] * rsum[n];
  }
}

// ---------------- Kernel 4: big contraction, bf16-image + global_load_lds DMA ----------------
// (unchanged from r12 — executed correctly there) grid (130, 8): bx = nq*2+eh, by = mc.
__global__ __launch_bounds__(256, 2) void attnv_kernel(
    const float* __restrict__ xn, const float* __restrict__ attn,
    const unsigned short* __restrict__ Wvb, float* __restrict__ inner_p) {
  __shared__ __align__(16) char sbuf[65536];  // xs[64][130] f32 OR dbuf 2x32KB bf16
  __shared__ float attnL[9 * 4 * 64];         // [mloc][hloc][b]
  float* xs = (float*)sbuf;
  unsigned short* wvb = (unsigned short*)sbuf;

  const int nq = blockIdx.x >> 1, eh = blockIdx.x & 1;
  const int mc = blockIdx.y;
  const int ms = (mc * 65) >> 3;
  const int cnt = (((mc + 1) * 65) >> 3) - ms;  // 8 (x7) or 9 (last)

  const int t = threadIdx.x;
  const int lane = t & 63;
  const int w = t >> 6;
  const int er = lane & 15, q = lane >> 4;
  const int rg = w & 1, cg = w >> 1;
  const int woff = w * 8192;

  const char* wvblk = (const char*)Wvb + ((size_t)nq * 65 + ms) * 65536 + eh * 32768;

  for (int i = t; i < 64 * 32; i += 256) {
    int b = i >> 5, c = (i & 31) << 2;
    float4 v = *(const float4*)(xn + ((size_t)b * 65 + nq) * 128 + c);
    float* dst = xs + b * 130 + c;
    dst[0] = v.x; dst[1] = v.y; dst[2] = v.z; dst[3] = v.w;
  }
  __syncthreads();
  short8 ah[2][4], al[2][4];
#pragma unroll
  for (int rt = 0; rt < 2; rt++) {
    const int arow = rg * 32 + rt * 16 + er;
#pragma unroll
    for (int s = 0; s < 4; s++) {
#pragma unroll
      for (int j = 0; j < 8; j++) {
        float xv = xs[arow * 130 + s * 32 + q * 8 + j];
        unsigned short hi = f2bf(xv);
        ah[rt][s][j] = (short)hi;
        al[rt][s][j] = (short)f2bf(xv - bf2f(hi));
      }
    }
  }
  __syncthreads();  // xs dead; sbuf becomes the Wv double buffer

  {
#pragma unroll
    for (int j = 0; j < 8; j++)
      gl_lds16(wvblk + woff + j * 1024 + (lane << 4),
               (char*)wvb + woff + j * 1024);
  }
  {
    const int hloc = t >> 6, b = t & 63;
    const int hg = eh * 4 + hloc;
    for (int mloc = 0; mloc < cnt; mloc++)
      attnL[(mloc * 4 + hloc) * 64 + b] =
          attn[(((size_t)(b * 8 + hg)) * 65 + nq) * 65 + ms + mloc];
  }
  __syncthreads();

  float4v acc[2][4];
#pragma unroll
  for (int rt = 0; rt < 2; rt++)
#pragma unroll
    for (int ct = 0; ct < 4; ct++)
      acc[rt][ct] = (float4v){0.f, 0.f, 0.f, 0.f};

  for (int i = 0; i < cnt; i++) {
    if (i + 1 < cnt) {
      const char* gs = wvblk + (size_t)(i + 1) * 65536;
      char* ls = (char*)wvb + ((i + 1) & 1) * 32768;
#pragma unroll
      for (int j = 0; j < 8; j++)
        gl_lds16(gs + woff + j * 1024 + (lane << 4), ls + woff + j * 1024);
    }
    const unsigned short* wb = wvb + (i & 1) * 16384;
    float4v P[2][4];
#pragma unroll
    for (int rt = 0; rt < 2; rt++)
#pragma unroll
      for (int ct = 0; ct < 4; ct++)
        P[rt][ct] = (float4v){0.f, 0.f, 0.f, 0.f};
    __builtin_amdgcn_s_setprio(1);
#pragma unroll
    for (int s = 0; s < 4; s++) {
      const int kc = 4 * s + q;
#pragma unroll
      for (int ct = 0; ct < 4; ct++) {
        short8 bf = *(const short8*)&wb[(cg * 64 + ct * 16 + er) * 128 + ((kc ^ er) << 3)];
        P[0][ct] = __builtin_amdgcn_mfma_f32_16x16x32_bf16(ah[0][s], bf, P[0][ct], 0, 0, 0);
        P[0][ct] = __builtin_amdgcn_mfma_f32_16x16x32_bf16(al[0][s], bf, P[0][ct], 0, 0, 0);
        P[1][ct] = __builtin_amdgcn_mfma_f32_16x16x32_bf16(ah[1][s], bf, P[1][ct], 0, 0, 0);
        P[1][ct] = __builtin_amdgcn_mfma_f32_16x16x32_bf16(al[1][s], bf, P[1][ct], 0, 0, 0);
      }
    }
    __builtin_amdgcn_s_setprio(0);
#pragma unroll
    for (int rt = 0; rt < 2; rt++) {
#pragma unroll
      for (int ct = 0; ct < 4; ct++) {
        const int hl = cg * 2 + (ct >> 1);
        const float* ap = attnL + (i * 4 + hl) * 64 + rg * 32 + rt * 16 + q * 4;
#pragma unroll
        for (int r = 0; r < 4; r++) acc[rt][ct][r] += ap[r] * P[rt][ct][r];
      }
    }
    __syncthreads();
  }

  float* ip = inner_p + (size_t)mc * 1064960;
#pragma unroll
  for (int rt = 0; rt < 2; rt++) {
#pragma unroll
    for (int ct = 0; ct < 4; ct++) {
      const int ecol = eh * 128 + cg * 64 + ct * 16 + er;
#pragma unroll
      for (int r = 0; r < 4; r++) {
        const int b = rg * 32 + rt * 16 + q * 4 + r;
        ip[((size_t)b * 65 + nq) * 256 + ecol] = acc[rt][ct][r];
      }
    }
  }
}

// ---------------- Kernel 5: out = (sum_j inner_p[j]) @ Wout + bout ----------------
__global__ __launch_bounds__(256) void outproj_kernel(
    const float* __restrict__ inner_p, const float* __restrict__ Wout,
    const float* __restrict__ bout, float* __restrict__ out) {
  __shared__ float isx[16][258];
  __shared__ float wsx[64][132];
  const int t = threadIdx.x;
  const int r0 = blockIdx.x * 16;
  for (int i = t; i < 16 * 64; i += 256) {
    int r = i >> 6, c = (i & 63) << 2;
    float4 a;
    a.x = 0.f; a.y = 0.f; a.z = 0.f; a.w = 0.f;
#pragma unroll
    for (int jj = 0; jj < 8; jj++) {
      float4 v = *(const float4*)(inner_p + (size_t)jj * 1064960 +
                                  (size_t)(r0 + r) * 256 + c);
      a.x += v.x; a.y += v.y; a.z += v.z; a.w += v.w;
    }
    float* dst = &isx[r][c];
    dst[0] = a.x; dst[1] = a.y; dst[2] = a.z; dst[3] = a.w;
  }
  const int rr = (t >> 5) * 2, cc = (t & 31) * 4;
  float acc[2][4] = {{0.f, 0.f, 0.f, 0.f}, {0.f, 0.f, 0.f, 0.f}};
  for (int kc = 0; kc < 4; kc++) {
    __syncthreads();
    for (int i = t; i < 64 * 32; i += 256) {
      int k = i >> 5, c = (i & 31) << 2;
      *(float4*)&wsx[k][c] = *(const float4*)(Wout + (size_t)(kc * 64 + k) * 128 + c);
    }
    __syncthreads();
#pragma unroll 8
    for (int k = 0; k < 64; k++) {
      float4 wv4 = *(const float4*)&wsx[k][cc];
      float x0 = isx[rr][kc * 64 + k];
      float x1 = isx[rr + 1][kc * 64 + k];
      acc[0][0] += x0 * wv4.x; acc[0][1] += x0 * wv4.y;
      acc[0][2] += x0 * wv4.z; acc[0][3] += x0 * wv4.w;
      acc[1][0] += x1 * wv4.x; acc[1][1] += x1 * wv4.y;
      acc[1][2] += x1 * wv4.z; acc[1][3] += x1 * wv4.w;
    }
  }
  float4 bb = *(const float4*)(bout + cc);
#pragma unroll
  for (int r = 0; r < 2; r++) {
    float4 o;
    o.x = acc[r][0] + bb.x; o.y = acc[r][1] + bb.y;
    o.z = acc[r][2] + bb.z; o.w = acc[r][3] + bb.w;
    *(float4*)(out + (size_t)(r0 + rr + r) * 128 + cc) = o;
  }
}

extern "C" void kernel_launch(void* const* d_in, const int* in_sizes, int n_in,
                              void* d_out, int out_size, void* d_ws, size_t ws_size,
                              hipStream_t stream) {
  const float* x     = (const float*)d_in[0];
  const float* gamma = (const float*)d_in[1];
  const float* beta  = (const float*)d_in[2];
  const float* Wqk   = (const float*)d_in[3];
  const float* Wv    = (const float*)d_in[4];
  const float* Wout  = (const float*)d_in[5];
  const float* bout  = (const float*)d_in[6];
  float* out = (float*)d_out;
  float* ws  = (float*)d_ws;

  float* xn      = ws;                    // 532,480 floats
  float* qk      = ws + 532480;           // 2,129,920
  float* attn    = ws + 2662400;          // 2,163,200
  float* inner_p = ws + 4825600;          // 8 x 1,064,960 = 8,519,680
  unsigned short* Wvb = (unsigned short*)(ws + 13500032);  // 276.9 MB bf16 image

  conv_kernel<<<4225, 256, 0, stream>>>(Wv, Wvb);
  ln_kernel<<<1040, 256, 0, stream>>>(x, gamma, beta, xn);
  qk_kernel<<<dim3(130, 8), 256, 0, stream>>>(xn, Wqk, qk);
  softmax_kernel<<<512, 256, 0, stream>>>(qk, attn);
  attnv_kernel<<<dim3(130, 8), 256, 0, stream>>>(xn, attn, Wvb, inner_p);
  outproj_kernel<<<260, 256, 0, stream>>>(inner_p, Wout, bout, out);
}

// Round 21
// 792.519 us; speedup vs baseline: 1.2367x; 1.1265x over previous
//
#include <hip/hip_runtime.h>

#define EPS 1e-5f

typedef __attribute__((ext_vector_type(8))) short short8;
typedef __attribute__((ext_vector_type(4))) float float4v;

__device__ __forceinline__ unsigned short f2bf(float x) {
  unsigned int u = __builtin_bit_cast(unsigned int, x);
  u += 0x7fffu + ((u >> 16) & 1u);   // RNE to bf16
  return (unsigned short)(u >> 16);
}
__device__ __forceinline__ float bf2f(unsigned short h) {
  unsigned int u = ((unsigned int)h) << 16;
  return __builtin_bit_cast(float, u);
}

// ---------------- Kernel 1: LayerNorm ----------------
__global__ __launch_bounds__(256) void ln_kernel(
    const float* __restrict__ x, const float* __restrict__ gamma,
    const float* __restrict__ beta, float* __restrict__ xn) {
  const int row = blockIdx.x * 4 + (threadIdx.x >> 6);
  const int lane = threadIdx.x & 63;
  const float2 v = ((const float2*)(x + (size_t)row * 128))[lane];
  float s = v.x + v.y;
#pragma unroll
  for (int off = 1; off < 64; off <<= 1) s += __shfl_xor(s, off);
  const float mu = s * (1.f / 128.f);
  const float dx = v.x - mu, dy = v.y - mu;
  float qv = dx * dx + dy * dy;
#pragma unroll
  for (int off = 1; off < 64; off <<= 1) qv += __shfl_xor(qv, off);
  const float rstd = 1.f / sqrtf(qv * (1.f / 128.f) + EPS);
  const float2 g = ((const float2*)gamma)[lane];
  const float2 be = ((const float2*)beta)[lane];
  float2 o;
  o.x = dx * rstd * g.x + be.x;
  o.y = dy * rstd * g.y + be.y;
  ((float2*)(xn + (size_t)row * 128))[lane] = o;
}

// ---------------- Kernel 2: qk = xn @ Wqk  [4160,128]x[128,512] ----------------
__global__ __launch_bounds__(256) void qk_kernel(
    const float* __restrict__ xn, const float* __restrict__ Wqk,
    float* __restrict__ qk) {
  __shared__ float xsx[32][130];
  __shared__ float wsx[128][68];
  const int t = threadIdx.x;
  const int r0 = blockIdx.x * 32, c0 = blockIdx.y * 64;
  for (int i = t; i < 32 * 32; i += 256) {
    int r = i >> 5, c = (i & 31) << 2;
    float4 v = *(const float4*)(xn + (size_t)(r0 + r) * 128 + c);
    float* dst = &xsx[r][c];
    dst[0] = v.x; dst[1] = v.y; dst[2] = v.z; dst[3] = v.w;
  }
  for (int i = t; i < 128 * 16; i += 256) {
    int k = i >> 4, c = (i & 15) << 2;
    *(float4*)&wsx[k][c] = *(const float4*)(Wqk + (size_t)k * 512 + c0 + c);
  }
  __syncthreads();
  const int rr = (t >> 4) * 2, cc = (t & 15) * 4;
  float acc[2][4] = {{0.f, 0.f, 0.f, 0.f}, {0.f, 0.f, 0.f, 0.f}};
  for (int k = 0; k < 128; k++) {
    float4 wv4 = *(const float4*)&wsx[k][cc];
    float x0 = xsx[rr][k], x1 = xsx[rr + 1][k];
    acc[0][0] += x0 * wv4.x; acc[0][1] += x0 * wv4.y;
    acc[0][2] += x0 * wv4.z; acc[0][3] += x0 * wv4.w;
    acc[1][0] += x1 * wv4.x; acc[1][1] += x1 * wv4.y;
    acc[1][2] += x1 * wv4.z; acc[1][3] += x1 * wv4.w;
  }
#pragma unroll
  for (int r = 0; r < 2; r++) {
    float4 o;
    o.x = acc[r][0]; o.y = acc[r][1]; o.z = acc[r][2]; o.w = acc[r][3];
    *(float4*)(qk + (size_t)(r0 + rr + r) * 512 + c0 + cc) = o;
  }
}

// ---------------- Kernel 3: dots + softmax ----------------
__global__ __launch_bounds__(256) void softmax_kernel(
    const float* __restrict__ qk, float* __restrict__ attn) {
  const int b = blockIdx.x >> 3, h = blockIdx.x & 7;
  __shared__ float qs[65][33];
  __shared__ float ks[65][33];
  __shared__ float dotsS[65][66];
  __shared__ float rsum[65];
  const int t = threadIdx.x;
  for (int i = t; i < 65 * 32; i += 256) {
    int n = i >> 5, d = i & 31;
    size_t base = ((size_t)b * 65 + n) * 512 + h * 32 + d;
    qs[n][d] = qk[base];
    ks[n][d] = qk[base + 256];
  }
  __syncthreads();
  const float scale = 0.17677669529663687f;  // 1/sqrt(32)
  for (int i = t; i < 65 * 65; i += 256) {
    int n = i / 65, mm = i - n * 65;
    float s = 0.f;
#pragma unroll
    for (int d = 0; d < 32; d++) s += qs[n][d] * ks[mm][d];
    dotsS[n][mm] = s * scale;
  }
  __syncthreads();
  if (t < 65) {
    float mx = -1e30f;
    for (int mm = 0; mm < 65; mm++) mx = fmaxf(mx, dotsS[t][mm]);
    float sum = 0.f;
    for (int mm = 0; mm < 65; mm++) {
      float e = __expf(dotsS[t][mm] - mx);
      dotsS[t][mm] = e;
      sum += e;
    }
    rsum[t] = 1.f / sum;
  }
  __syncthreads();
  const size_t obase = ((size_t)b * 8 + h) * 65 * 65;
  for (int i = t; i < 65 * 65; i += 256) {
    int n = i / 65;
    attn[obase + i] = dotsS[n][i - n * 65] * rsum[n];
  }
}

// ---------------- Kernel 4: fused big contraction, VECTORIZED Wv reads ----------------
// grid (130, 8): bx = nq*2+eh (e-half of 256 cols), by = mc (8 m-chunks of 8-9).
// Single pass over Wv (554MB total, 16B/lane float4 reads: wave = 4x512B segments).
// Thread t owns d-chunk kc=t>>4 (8 d) x e-group eg=t&15 (8 e): loads 8d x 8e fp32
// sub-block (16 float4), register-transposes, writes 8x short8 ALONG-D into the
// XOR-swizzled k-major LDS dbuf (same image the verified MFMA phase consumes).
// Partial sums -> inner_p[mc] with plain stores (no atomics).
__global__ __launch_bounds__(256, 2) void attnv_kernel(
    const float* __restrict__ xn, const float* __restrict__ attn,
    const float* __restrict__ Wv, float* __restrict__ inner_p) {
  __shared__ __align__(16) char sbuf[65536];  // xs[64][130] f32 OR dbuf 2x32KB bf16
  __shared__ float attnL[9 * 4 * 64];         // [mloc][hloc][b]
  float* xs = (float*)sbuf;
  unsigned short* wvb = (unsigned short*)sbuf;

  const int nq = blockIdx.x >> 1, eh = blockIdx.x & 1;
  const int mc = blockIdx.y;
  const int ms = (mc * 65) >> 3;
  const int cnt = (((mc + 1) * 65) >> 3) - ms;  // 8 (x7) or 9 (last)

  const int t = threadIdx.x;
  const int lane = t & 63;
  const int w = t >> 6;
  const int er = lane & 15, q = lane >> 4;
  const int rg = w & 1, cg = w >> 1;

  // staging coords: d-chunk kc (8 consecutive d), e-group eg (8 consecutive e)
  const int kc = t >> 4;      // 0..15
  const int eg = t & 15;      // 0..15
  const float* wvsrc = Wv + ((size_t)nq * 65 + ms) * 32768
                          + (size_t)(kc * 8) * 256 + eh * 128 + eg * 8;

  float4v sA[8][2];  // [d-within-chunk][e-half]: 8d x 8e fp32

#define ISSUE(mm) do {                                                        \
    const float* p_ = wvsrc + (size_t)(mm) * 32768;                           \
    _Pragma("unroll")                                                         \
    for (int j_ = 0; j_ < 8; j_++) {                                          \
      sA[j_][0] = *(const float4v*)(p_ + (size_t)j_ * 256);                   \
      sA[j_][1] = *(const float4v*)(p_ + (size_t)j_ * 256 + 4);               \
    }                                                                         \
  } while (0)

  // register transpose: for each local e, pack short8 along d (chunk kc),
  // store at row e_loc, position (kc ^ (e_loc&15)) -- same involution the
  // MFMA phase reads back with (kc_r ^ er).
#define CONVWRITE(buf) do {                                                   \
    unsigned short* wb_ = wvb + (size_t)(buf) * 16384;                        \
    _Pragma("unroll")                                                         \
    for (int i_ = 0; i_ < 8; i_++) {                                          \
      const int el_ = eg * 8 + i_;                                            \
      short8 pk_;                                                             \
      _Pragma("unroll")                                                       \
      for (int j_ = 0; j_ < 8; j_++)                                          \
        pk_[j_] = (short)f2bf(sA[j_][i_ >> 2][i_ & 3]);                       \
      *(short8*)&wb_[el_ * 128 + ((kc ^ (el_ & 15)) << 3)] = pk_;             \
    }                                                                         \
  } while (0)

  ISSUE(0);  // m=ms loads fly during all prologue staging

  // ---- prologue A: xn rows -> xs, then A-fragments (hi/lo bf16) ----
  for (int i = t; i < 64 * 32; i += 256) {
    int b = i >> 5, c = (i & 31) << 2;
    float4 v = *(const float4*)(xn + ((size_t)b * 65 + nq) * 128 + c);
    float* dst = xs + b * 130 + c;
    dst[0] = v.x; dst[1] = v.y; dst[2] = v.z; dst[3] = v.w;
  }
  __syncthreads();
  short8 ah[2][4], al[2][4];
#pragma unroll
  for (int rt = 0; rt < 2; rt++) {
    const int arow = rg * 32 + rt * 16 + er;
#pragma unroll
    for (int s = 0; s < 4; s++) {
#pragma unroll
      for (int j = 0; j < 8; j++) {
        float xv = xs[arow * 130 + s * 32 + q * 8 + j];
        unsigned short hi = f2bf(xv);
        ah[rt][s][j] = (short)hi;
        al[rt][s][j] = (short)f2bf(xv - bf2f(hi));
      }
    }
  }
  __syncthreads();  // xs dead; sbuf becomes the Wv double buffer

  // ---- prologue B: convert+write m=ms into buf0; attn chunk -> attnL ----
  CONVWRITE(0);
  {
    const int hloc = t >> 6, b = t & 63;
    const int hg = eh * 4 + hloc;
    for (int mloc = 0; mloc < cnt; mloc++)
      attnL[(mloc * 4 + hloc) * 64 + b] =
          attn[(((size_t)(b * 8 + hg)) * 65 + nq) * 65 + ms + mloc];
  }
  __syncthreads();

  float4v acc[2][4];
#pragma unroll
  for (int rt = 0; rt < 2; rt++)
#pragma unroll
    for (int ct = 0; ct < 4; ct++)
      acc[rt][ct] = (float4v){0.f, 0.f, 0.f, 0.f};

  for (int i = 0; i < cnt; i++) {
    if (i + 1 < cnt) ISSUE(i + 1);  // next-m loads hide under MFMA phase
    const unsigned short* wb = wvb + (i & 1) * 16384;
    float4v P[2][4];
#pragma unroll
    for (int rt = 0; rt < 2; rt++)
#pragma unroll
      for (int ct = 0; ct < 4; ct++)
        P[rt][ct] = (float4v){0.f, 0.f, 0.f, 0.f};
    __builtin_amdgcn_s_setprio(1);
#pragma unroll
    for (int s = 0; s < 4; s++) {
      const int kcr = 4 * s + q;
#pragma unroll
      for (int ct = 0; ct < 4; ct++) {
        short8 bf = *(const short8*)&wb[(cg * 64 + ct * 16 + er) * 128 + ((kcr ^ er) << 3)];
        P[0][ct] = __builtin_amdgcn_mfma_f32_16x16x32_bf16(ah[0][s], bf, P[0][ct], 0, 0, 0);
        P[0][ct] = __builtin_amdgcn_mfma_f32_16x16x32_bf16(al[0][s], bf, P[0][ct], 0, 0, 0);
        P[1][ct] = __builtin_amdgcn_mfma_f32_16x16x32_bf16(ah[1][s], bf, P[1][ct], 0, 0, 0);
        P[1][ct] = __builtin_amdgcn_mfma_f32_16x16x32_bf16(al[1][s], bf, P[1][ct], 0, 0, 0);
      }
    }
    __builtin_amdgcn_s_setprio(0);
#pragma unroll
    for (int rt = 0; rt < 2; rt++) {
#pragma unroll
      for (int ct = 0; ct < 4; ct++) {
        const int hl = cg * 2 + (ct >> 1);
        const float* ap = attnL + (i * 4 + hl) * 64 + rg * 32 + rt * 16 + q * 4;
#pragma unroll
        for (int r = 0; r < 4; r++) acc[rt][ct][r] += ap[r] * P[rt][ct][r];
      }
    }
    if (i + 1 < cnt) CONVWRITE((i + 1) & 1);
    __syncthreads();
  }

#undef ISSUE
#undef CONVWRITE

  // ---- epilogue: plain stores into this mc's private partial buffer ----
  float* ip = inner_p + (size_t)mc * 1064960;
#pragma unroll
  for (int rt = 0; rt < 2; rt++) {
#pragma unroll
    for (int ct = 0; ct < 4; ct++) {
      const int ecol = eh * 128 + cg * 64 + ct * 16 + er;
#pragma unroll
      for (int r = 0; r < 4; r++) {
        const int b = rg * 32 + rt * 16 + q * 4 + r;
        ip[((size_t)b * 65 + nq) * 256 + ecol] = acc[rt][ct][r];
      }
    }
  }
}

// ---------------- Kernel 5: out = (sum_j inner_p[j]) @ Wout + bout ----------------
__global__ __launch_bounds__(256) void outproj_kernel(
    const float* __restrict__ inner_p, const float* __restrict__ Wout,
    const float* __restrict__ bout, float* __restrict__ out) {
  __shared__ float isx[16][258];
  __shared__ float wsx[64][132];
  const int t = threadIdx.x;
  const int r0 = blockIdx.x * 16;
  for (int i = t; i < 16 * 64; i += 256) {
    int r = i >> 6, c = (i & 63) << 2;
    float4 a;
    a.x = 0.f; a.y = 0.f; a.z = 0.f; a.w = 0.f;
#pragma unroll
    for (int jj = 0; jj < 8; jj++) {
      float4 v = *(const float4*)(inner_p + (size_t)jj * 1064960 +
                                  (size_t)(r0 + r) * 256 + c);
      a.x += v.x; a.y += v.y; a.z += v.z; a.w += v.w;
    }
    float* dst = &isx[r][c];
    dst[0] = a.x; dst[1] = a.y; dst[2] = a.z; dst[3] = a.w;
  }
  const int rr = (t >> 5) * 2, cc = (t & 31) * 4;
  float acc[2][4] = {{0.f, 0.f, 0.f, 0.f}, {0.f, 0.f, 0.f, 0.f}};
  for (int kc = 0; kc < 4; kc++) {
    __syncthreads();
    for (int i = t; i < 64 * 32; i += 256) {
      int k = i >> 5, c = (i & 31) << 2;
      *(float4*)&wsx[k][c] = *(const float4*)(Wout + (size_t)(kc * 64 + k) * 128 + c);
    }
    __syncthreads();
#pragma unroll 8
    for (int k = 0; k < 64; k++) {
      float4 wv4 = *(const float4*)&wsx[k][cc];
      float x0 = isx[rr][kc * 64 + k];
      float x1 = isx[rr + 1][kc * 64 + k];
      acc[0][0] += x0 * wv4.x; acc[0][1] += x0 * wv4.y;
      acc[0][2] += x0 * wv4.z; acc[0][3] += x0 * wv4.w;
      acc[1][0] += x1 * wv4.x; acc[1][1] += x1 * wv4.y;
      acc[1][2] += x1 * wv4.z; acc[1][3] += x1 * wv4.w;
    }
  }
  float4 bb = *(const float4*)(bout + cc);
#pragma unroll
  for (int r = 0; r < 2; r++) {
    float4 o;
    o.x = acc[r][0] + bb.x; o.y = acc[r][1] + bb.y;
    o.z = acc[r][2] + bb.z; o.w = acc[r][3] + bb.w;
    *(float4*)(out + (size_t)(r0 + rr + r) * 128 + cc) = o;
  }
}

extern "C" void kernel_launch(void* const* d_in, const int* in_sizes, int n_in,
                              void* d_out, int out_size, void* d_ws, size_t ws_size,
                              hipStream_t stream) {
  const float* x     = (const float*)d_in[0];
  const float* gamma = (const float*)d_in[1];
  const float* beta  = (const float*)d_in[2];
  const float* Wqk   = (const float*)d_in[3];
  const float* Wv    = (const float*)d_in[4];
  const float* Wout  = (const float*)d_in[5];
  const float* bout  = (const float*)d_in[6];
  float* out = (float*)d_out;
  float* ws  = (float*)d_ws;

  float* xn      = ws;                    // 532,480 floats
  float* qk      = ws + 532480;           // 2,129,920
  float* attn    = ws + 2662400;          // 2,163,200
  float* inner_p = ws + 4825600;          // 8 x 1,064,960 = 8,519,680

  ln_kernel<<<1040, 256, 0, stream>>>(x, gamma, beta, xn);
  qk_kernel<<<dim3(130, 8), 256, 0, stream>>>(xn, Wqk, qk);
  softmax_kernel<<<512, 256, 0, stream>>>(qk, attn);
  attnv_kernel<<<dim3(130, 8), 256, 0, stream>>>(xn, attn, Wv, inner_p);
  outproj_kernel<<<260, 256, 0, stream>>>(inner_p, Wout, bout, out);
}